// Round 1
// baseline (109.190 us; speedup 1.0000x reference)
//
#include <hip/hip_runtime.h>

#define N 32768
#define P 8192
#define SLICES 8
#define XPB 64                 // x-values per block
#define PATS_PER_SLICE (P / SLICES)   // 1024

// f = log2(e) / (2 * sigma^2), sigma^2 = 1.44
// exp(-Dsq/(2s)) = exp2(-Dsq * f). Per-x |x|^2 term cancels in num/den.
#define RBF_F 0.50093577808645257f   // 1.4426950408889634 / 2.88

static __device__ __forceinline__ float fast_exp2(float x) {
#if __has_builtin(__builtin_amdgcn_exp2f)
    return __builtin_amdgcn_exp2f(x);
#else
    return exp2f(x);
#endif
}

// Precompute per-pattern constants: (c0, c1, c2, w)
//   c0 = 2*f*p0, c1 = 2*f*p1, c2 = -f*(p0^2+p1^2), w = W2[i]
__global__ void prep_kernel(const float* __restrict__ pat,
                            const float* __restrict__ w2,
                            float4* __restrict__ c) {
    int i = blockIdx.x * blockDim.x + threadIdx.x;
    if (i < P) {
        float p0 = pat[2 * i];
        float p1 = pat[2 * i + 1];
        float4 v;
        v.x = 2.0f * RBF_F * p0;
        v.y = 2.0f * RBF_F * p1;
        v.z = -RBF_F * (p0 * p0 + p1 * p1);
        v.w = w2[i];
        c[i] = v;
    }
}

__global__ __launch_bounds__(SLICES * XPB) void
rbf_kernel(const float* __restrict__ X,
           const float4* __restrict__ c,
           float* __restrict__ out) {
    const int t  = threadIdx.x;
    const int xl = t & (XPB - 1);          // 0..63 — x within block
    const int xi = blockIdx.x * XPB + xl;  // global x index
    // slice is constant across each 64-lane wave; force SGPR so pattern
    // loads become scalar (s_load) — keeps the vector-mem pipe idle.
    const int slice = __builtin_amdgcn_readfirstlane(t >> 6);

    const float2 xv = ((const float2*)X)[xi];
    const float x0 = xv.x, x1 = xv.y;

    const float4* __restrict__ cp = c + slice * PATS_PER_SLICE;

    float n0 = 0.f, n1 = 0.f, n2 = 0.f, n3 = 0.f;
    float d0 = 0.f, d1 = 0.f, d2 = 0.f, d3 = 0.f;

#pragma unroll 4
    for (int j = 0; j < PATS_PER_SLICE; j += 4) {
        float4 a = cp[j + 0];
        float4 b = cp[j + 1];
        float4 e = cp[j + 2];
        float4 g = cp[j + 3];

        float k0 = fast_exp2(fmaf(a.y, x1, fmaf(a.x, x0, a.z)));
        float k1 = fast_exp2(fmaf(b.y, x1, fmaf(b.x, x0, b.z)));
        float k2 = fast_exp2(fmaf(e.y, x1, fmaf(e.x, x0, e.z)));
        float k3 = fast_exp2(fmaf(g.y, x1, fmaf(g.x, x0, g.z)));

        d0 += k0; n0 = fmaf(k0, a.w, n0);
        d1 += k1; n1 = fmaf(k1, b.w, n1);
        d2 += k2; n2 = fmaf(k2, e.w, n2);
        d3 += k3; n3 = fmaf(k3, g.w, n3);
    }

    float num = (n0 + n1) + (n2 + n3);
    float den = (d0 + d1) + (d2 + d3);

    __shared__ float snum[SLICES][XPB];
    __shared__ float sden[SLICES][XPB];
    snum[slice][xl] = num;
    sden[slice][xl] = den;
    __syncthreads();

    if (t < XPB) {
        float nn = 0.f, dd = 0.f;
#pragma unroll
        for (int s = 0; s < SLICES; ++s) {
            nn += snum[s][t];
            dd += sden[s][t];
        }
        out[blockIdx.x * XPB + t] = nn / dd;
    }
}

extern "C" void kernel_launch(void* const* d_in, const int* in_sizes, int n_in,
                              void* d_out, int out_size, void* d_ws, size_t ws_size,
                              hipStream_t stream) {
    const float* X   = (const float*)d_in[0];   // [32768, 2]
    const float* pat = (const float*)d_in[1];   // [8192, 2]
    const float* w2  = (const float*)d_in[2];   // [8192]
    float* out = (float*)d_out;                 // [32768]
    float4* c = (float4*)d_ws;                  // 8192 * 16 B = 128 KB

    prep_kernel<<<(P + 255) / 256, 256, 0, stream>>>(pat, w2, c);
    rbf_kernel<<<N / XPB, SLICES * XPB, 0, stream>>>(X, c, out);
}

// Round 2
// 99.149 us; speedup vs baseline: 1.1013x; 1.1013x over previous
//
#include <hip/hip_runtime.h>

#define N 32768
#define P 8192
#define SLICES 16
#define XPB 64                         // x-values per block (one wave-width)
#define PATS_PER_SLICE (P / SLICES)    // 512
#define PAIRS_PER_SLICE (PATS_PER_SLICE / 2)  // 256

// f = log2(e) / (2 * sigma^2), sigma^2 = 1.44
// exp(-Dsq/(2s^2)) = exp2(-Dsq * f). Per-x |x|^2 term cancels in num/den.
#define RBF_F 0.50093577808645257f     // 1.4426950408889634 / 2.88

typedef float v2f __attribute__((ext_vector_type(2)));

static __device__ __forceinline__ float fast_exp2(float x) {
#if __has_builtin(__builtin_amdgcn_exp2f)
    return __builtin_amdgcn_exp2f(x);
#else
    return exp2f(x);
#endif
}

// Pair-interleaved constants: for pair q (patterns 2q, 2q+1), two float4s:
//   c[2q]   = { c0(2q), c0(2q+1), c1(2q), c1(2q+1) }
//   c[2q+1] = { c2(2q), c2(2q+1), w(2q),  w(2q+1)  }
// with c0 = 2*f*p0, c1 = 2*f*p1, c2 = -f*|p|^2  (pk-friendly layout).
__global__ void prep_kernel(const float* __restrict__ pat,
                            const float* __restrict__ w2,
                            float4* __restrict__ c) {
    int q = blockIdx.x * blockDim.x + threadIdx.x;   // pair index, [0, P/2)
    if (q < P / 2) {
        float p00 = pat[4 * q + 0], p01 = pat[4 * q + 1];   // pattern 2q
        float p10 = pat[4 * q + 2], p11 = pat[4 * q + 3];   // pattern 2q+1
        float4 a, b;
        a.x = 2.0f * RBF_F * p00;  a.y = 2.0f * RBF_F * p10;
        a.z = 2.0f * RBF_F * p01;  a.w = 2.0f * RBF_F * p11;
        b.x = -RBF_F * (p00 * p00 + p01 * p01);
        b.y = -RBF_F * (p10 * p10 + p11 * p11);
        b.z = w2[2 * q];           b.w = w2[2 * q + 1];
        c[2 * q]     = a;
        c[2 * q + 1] = b;
    }
}

__global__ __launch_bounds__(SLICES * XPB) void
rbf_kernel(const float* __restrict__ X,
           const float4* __restrict__ c,
           float* __restrict__ out) {
    const int t  = threadIdx.x;
    const int xl = t & (XPB - 1);
    const int xi = blockIdx.x * XPB + xl;
    // slice is constant across each 64-lane wave; force SGPR so pattern
    // loads become scalar (s_load) — vector-mem pipe stays idle.
    const int slice = __builtin_amdgcn_readfirstlane(t >> 6);

    const float2 xv = ((const float2*)X)[xi];
    const v2f x0v = { xv.x, xv.x };
    const v2f x1v = { xv.y, xv.y };

    // float4 units: 2 per pair
    const float4* __restrict__ cp = c + (size_t)slice * (2 * PAIRS_PER_SLICE);

    v2f n0 = {0.f, 0.f}, n1 = {0.f, 0.f};
    v2f d0 = {0.f, 0.f}, d1 = {0.f, 0.f};

#pragma unroll 2
    for (int q = 0; q < PAIRS_PER_SLICE; q += 2) {
        float4 a0 = cp[2 * q + 0];
        float4 a1 = cp[2 * q + 1];
        float4 b0 = cp[2 * q + 2];
        float4 b1 = cp[2 * q + 3];

        v2f ta = __builtin_elementwise_fma((v2f){a0.x, a0.y}, x0v,
                                           (v2f){a1.x, a1.y});
        ta = __builtin_elementwise_fma((v2f){a0.z, a0.w}, x1v, ta);
        v2f tb = __builtin_elementwise_fma((v2f){b0.x, b0.y}, x0v,
                                           (v2f){b1.x, b1.y});
        tb = __builtin_elementwise_fma((v2f){b0.z, b0.w}, x1v, tb);

        v2f ka = { fast_exp2(ta.x), fast_exp2(ta.y) };
        v2f kb = { fast_exp2(tb.x), fast_exp2(tb.y) };

        d0 += ka;                                          // v_pk_add_f32
        n0 = __builtin_elementwise_fma(ka, (v2f){a1.z, a1.w}, n0);
        d1 += kb;
        n1 = __builtin_elementwise_fma(kb, (v2f){b1.z, b1.w}, n1);
    }

    v2f nv = n0 + n1;
    v2f dv = d0 + d1;
    float num = nv.x + nv.y;
    float den = dv.x + dv.y;

    __shared__ float snum[SLICES][XPB];
    __shared__ float sden[SLICES][XPB];
    snum[slice][xl] = num;
    sden[slice][xl] = den;
    __syncthreads();

    if (t < XPB) {
        float nn = 0.f, dd = 0.f;
#pragma unroll
        for (int s = 0; s < SLICES; ++s) {
            nn += snum[s][t];
            dd += sden[s][t];
        }
        out[blockIdx.x * XPB + t] = nn / dd;
    }
}

extern "C" void kernel_launch(void* const* d_in, const int* in_sizes, int n_in,
                              void* d_out, int out_size, void* d_ws, size_t ws_size,
                              hipStream_t stream) {
    const float* X   = (const float*)d_in[0];   // [32768, 2]
    const float* pat = (const float*)d_in[1];   // [8192, 2]
    const float* w2  = (const float*)d_in[2];   // [8192]
    float* out = (float*)d_out;                 // [32768]
    float4* c = (float4*)d_ws;                  // 8192 * 16 B = 128 KB

    prep_kernel<<<(P / 2 + 255) / 256, 256, 0, stream>>>(pat, w2, c);
    rbf_kernel<<<N / XPB, SLICES * XPB, 0, stream>>>(X, c, out);
}

// Round 3
// 96.253 us; speedup vs baseline: 1.1344x; 1.0301x over previous
//
#include <hip/hip_runtime.h>

#define N 32768
#define P 8192
#define TILE 1024                 // patterns per LDS tile (16 KB)
#define NTILES (P / TILE)         // 8
#define XG 4                      // x-groups per block
#define MX 8                      // x-values per wave (wave-uniform)
#define XPB (XG * MX)             // 32 x per block
#define THREADS 512               // 8 waves: (xg, pattern-half)
#define NBLK (N / XPB)            // 1024 blocks

// f = log2(e) / (2*sigma^2), sigma^2 = 1.44; per-x |x|^2 cancels in num/den.
#define RBF_F 0.50093577808645257f

typedef float v2f __attribute__((ext_vector_type(2)));

#define AS1 __attribute__((address_space(1)))
#define AS3 __attribute__((address_space(3)))

static __device__ __forceinline__ float fast_exp2(float x) {
#if __has_builtin(__builtin_amdgcn_exp2f)
    return __builtin_amdgcn_exp2f(x);
#else
    return exp2f(x);
#endif
}

// c[i] = { 2f*p0, 2f*p1, -f*|p|^2, w }
__global__ void prep_kernel(const float* __restrict__ pat,
                            const float* __restrict__ w2,
                            float4* __restrict__ c) {
    int i = blockIdx.x * blockDim.x + threadIdx.x;
    if (i < P) {
        float p0 = pat[2 * i];
        float p1 = pat[2 * i + 1];
        float4 v;
        v.x = 2.0f * RBF_F * p0;
        v.y = 2.0f * RBF_F * p1;
        v.z = -RBF_F * (p0 * p0 + p1 * p1);
        v.w = w2[i];
        c[i] = v;
    }
}

__global__ __launch_bounds__(THREADS, 8) void
rbf_kernel(const float* __restrict__ X,
           const float4* __restrict__ c,
           float* __restrict__ out) {
    __shared__ float4 buf[2][TILE];          // double-buffered pattern tiles
    __shared__ float red[XG][2][MX][2];      // cross-wave partials

    const int t    = threadIdx.x;
    const int lane = t & 63;
    const int w    = __builtin_amdgcn_readfirstlane(t >> 6);  // 0..7
    const int xg   = w >> 1;                 // x-group 0..3
    const int ph   = w & 1;                  // pattern half within tile

    // 8 wave-uniform x-values -> SGPRs, packed as x-pairs for pk math
    const int xbase = blockIdx.x * XPB + xg * MX;
    v2f xs0[MX / 2], xs1[MX / 2];
    {
        const float2* Xp = (const float2*)X;
#pragma unroll
        for (int i = 0; i < MX / 2; ++i) {
            float2 xa = Xp[xbase + 2 * i];
            float2 xb = Xp[xbase + 2 * i + 1];
            xs0[i] = (v2f){xa.x, xb.x};
            xs1[i] = (v2f){xa.y, xb.y};
        }
    }

    v2f num[MX / 2], den[MX / 2];
#pragma unroll
    for (int i = 0; i < MX / 2; ++i) {
        num[i] = (v2f){0.f, 0.f};
        den[i] = (v2f){0.f, 0.f};
    }

    // stage tile -> LDS buffer, 16 B per lane per round, 2 rounds (512 thr)
    auto stage = [&](int tile, int bsel) {
        const float4* src = c + tile * TILE;
        __builtin_amdgcn_global_load_lds((const AS1 void*)(src + t),
                                         (AS3 void*)&buf[bsel][t], 16, 0, 0);
        __builtin_amdgcn_global_load_lds((const AS1 void*)(src + t + 512),
                                         (AS3 void*)&buf[bsel][t + 512], 16, 0, 0);
    };

    stage(0, 0);
    __syncthreads();   // drains vmcnt before first compute

    for (int tile = 0; tile < NTILES; ++tile) {
        const int bsel = tile & 1;
        if (tile + 1 < NTILES) stage(tile + 1, bsel ^ 1);  // prefetch next

        const float4* cur = &buf[bsel][ph * (TILE / 2)];
#pragma unroll 2
        for (int j = 0; j < TILE / 2; j += 64) {
            float4 cc = cur[j + lane];        // ds_read_b128, conflict-free
#pragma unroll
            for (int i = 0; i < MX / 2; ++i) {
                v2f tt = __builtin_elementwise_fma((v2f){cc.x, cc.x}, xs0[i],
                                                   (v2f){cc.z, cc.z});
                tt = __builtin_elementwise_fma((v2f){cc.y, cc.y}, xs1[i], tt);
                v2f k = (v2f){fast_exp2(tt.x), fast_exp2(tt.y)};
                den[i] += k;                                       // v_pk_add_f32
                num[i] = __builtin_elementwise_fma(k, (v2f){cc.w, cc.w}, num[i]);
            }
        }
        __syncthreads();   // next-tile staged AND cur fully consumed
    }

    // reduce the per-lane pattern-partials across the 64 lanes
#pragma unroll
    for (int m = 1; m < 64; m <<= 1) {
#pragma unroll
        for (int i = 0; i < MX / 2; ++i) {
            num[i].x += __shfl_xor(num[i].x, m, 64);
            num[i].y += __shfl_xor(num[i].y, m, 64);
            den[i].x += __shfl_xor(den[i].x, m, 64);
            den[i].y += __shfl_xor(den[i].y, m, 64);
        }
    }

    if (lane == 0) {
#pragma unroll
        for (int i = 0; i < MX / 2; ++i) {
            red[xg][ph][2 * i][0]     = num[i].x;
            red[xg][ph][2 * i][1]     = den[i].x;
            red[xg][ph][2 * i + 1][0] = num[i].y;
            red[xg][ph][2 * i + 1][1] = den[i].y;
        }
    }
    __syncthreads();

    if (t < XPB) {
        int g = t >> 3, xi = t & 7;
        float nn = red[g][0][xi][0] + red[g][1][xi][0];
        float dd = red[g][0][xi][1] + red[g][1][xi][1];
        out[blockIdx.x * XPB + t] = nn / dd;
    }
}

extern "C" void kernel_launch(void* const* d_in, const int* in_sizes, int n_in,
                              void* d_out, int out_size, void* d_ws, size_t ws_size,
                              hipStream_t stream) {
    const float* X   = (const float*)d_in[0];   // [32768, 2]
    const float* pat = (const float*)d_in[1];   // [8192, 2]
    const float* w2  = (const float*)d_in[2];   // [8192]
    float* out = (float*)d_out;                 // [32768]
    float4* c = (float4*)d_ws;                  // 8192 * 16 B = 128 KB

    prep_kernel<<<(P + 255) / 256, 256, 0, stream>>>(pat, w2, c);
    rbf_kernel<<<NBLK, THREADS, 0, stream>>>(X, c, out);
}

// Round 4
// 94.426 us; speedup vs baseline: 1.1563x; 1.0193x over previous
//
#include <hip/hip_runtime.h>

#define N 32768
#define P 8192
#define MX 8                          // x-values per wave (wave-uniform)
#define XG 2                          // x-groups per block
#define PH 2                          // pattern halves
#define THREADS (XG * PH * 64)        // 256
#define XPB (XG * MX)                 // 16 x per block
#define NBLK (N / XPB)                // 2048
#define PAIRS (P / 2)                 // 4096 pattern-pairs
#define PAIRS_PER_PH (PAIRS / PH)     // 2048
#define ITERS (PAIRS_PER_PH / 64)     // 32 (power of 2 — wrap prefetch)

// f = log2(e)/(2*sigma^2), sigma^2 = 1.44; per-x |x|^2 cancels in num/den.
#define RBF_F 0.50093577808645257f

typedef float v2f __attribute__((ext_vector_type(2)));

static __device__ __forceinline__ float fast_exp2(float x) {
#if __has_builtin(__builtin_amdgcn_exp2f)
    return __builtin_amdgcn_exp2f(x);
#else
    return exp2f(x);
#endif
}

// Pair-interleaved constants for pattern pair q = (2q, 2q+1):
//   c[2q]   = { c0(2q), c0(2q+1), c1(2q), c1(2q+1) }
//   c[2q+1] = { c2(2q), c2(2q+1), w(2q),  w(2q+1)  }
// pk ops consume the loaded register pairs directly — no repacking movs.
__global__ void prep_kernel(const float* __restrict__ pat,
                            const float* __restrict__ w2,
                            float4* __restrict__ c) {
    int q = blockIdx.x * blockDim.x + threadIdx.x;
    if (q < P / 2) {
        float p00 = pat[4 * q + 0], p01 = pat[4 * q + 1];
        float p10 = pat[4 * q + 2], p11 = pat[4 * q + 3];
        float4 a, b;
        a.x = 2.0f * RBF_F * p00;  a.y = 2.0f * RBF_F * p10;
        a.z = 2.0f * RBF_F * p01;  a.w = 2.0f * RBF_F * p11;
        b.x = -RBF_F * (p00 * p00 + p01 * p01);
        b.y = -RBF_F * (p10 * p10 + p11 * p11);
        b.z = w2[2 * q];           b.w = w2[2 * q + 1];
        c[2 * q]     = a;
        c[2 * q + 1] = b;
    }
}

__global__ __launch_bounds__(THREADS) void
rbf_kernel(const float* __restrict__ X,
           const float4* __restrict__ c,
           float* __restrict__ out) {
    const int t    = threadIdx.x;
    const int lane = t & 63;
    const int w    = __builtin_amdgcn_readfirstlane(t >> 6);  // 0..3
    const int xg   = w >> 1;
    const int ph   = w & 1;

    // 8 wave-uniform x-values, hoisted as persistent splat pairs
    const int xb = blockIdx.x * XPB + xg * MX;
    const float2* Xp = (const float2*)X;
    v2f xs0[MX], xs1[MX];
#pragma unroll
    for (int i = 0; i < MX; ++i) {
        float2 xv = Xp[xb + i];
        xs0[i] = (v2f){xv.x, xv.x};
        xs1[i] = (v2f){xv.y, xv.y};
    }

    v2f num2[MX], den2[MX];
#pragma unroll
    for (int i = 0; i < MX; ++i) {
        num2[i] = (v2f){0.f, 0.f};
        den2[i] = (v2f){0.f, 0.f};
    }

    // this wave's pattern-pair stream (L2-resident, coalesced 2 KB/wave/iter)
    const float4* __restrict__ C4 = c + (size_t)ph * (2 * PAIRS_PER_PH);

    float4 a = C4[2 * lane];
    float4 b = C4[2 * lane + 1];

    for (int j = 0; j < ITERS; ++j) {
        // branch-free wrapped prefetch of next iteration's pair
        const int qn = (((j + 1) & (ITERS - 1)) << 6) + lane;
        float4 an = C4[2 * qn];
        float4 bn = C4[2 * qn + 1];

#pragma unroll
        for (int i = 0; i < MX; ++i) {
            // arg for patterns (2q, 2q+1) at x_i — all operands are direct
            // register pairs: v_pk_fma_f32 ×2, v_exp_f32 ×2, v_pk_add, v_pk_fma
            v2f tt = __builtin_elementwise_fma((v2f){a.x, a.y}, xs0[i],
                                               (v2f){b.x, b.y});
            tt = __builtin_elementwise_fma((v2f){a.z, a.w}, xs1[i], tt);
            v2f k = (v2f){fast_exp2(tt.x), fast_exp2(tt.y)};
            den2[i] += k;
            num2[i] = __builtin_elementwise_fma(k, (v2f){b.z, b.w}, num2[i]);
        }
        a = an;
        b = bn;
    }

    // fold pattern-pair halves, then 6-step butterfly across the wave
    float num[MX], den[MX];
#pragma unroll
    for (int i = 0; i < MX; ++i) {
        num[i] = num2[i].x + num2[i].y;
        den[i] = den2[i].x + den2[i].y;
    }
#pragma unroll
    for (int m = 1; m < 64; m <<= 1) {
#pragma unroll
        for (int i = 0; i < MX; ++i) {
            num[i] += __shfl_xor(num[i], m, 64);
            den[i] += __shfl_xor(den[i], m, 64);
        }
    }

    __shared__ float red[XG][PH][MX][2];
    if (lane == 0) {
#pragma unroll
        for (int i = 0; i < MX; ++i) {
            red[xg][ph][i][0] = num[i];
            red[xg][ph][i][1] = den[i];
        }
    }
    __syncthreads();

    if (t < XPB) {
        int g = t >> 3, xi = t & 7;
        float nn = red[g][0][xi][0] + red[g][1][xi][0];
        float dd = red[g][0][xi][1] + red[g][1][xi][1];
        out[blockIdx.x * XPB + t] = nn / dd;
    }
}

extern "C" void kernel_launch(void* const* d_in, const int* in_sizes, int n_in,
                              void* d_out, int out_size, void* d_ws, size_t ws_size,
                              hipStream_t stream) {
    const float* X   = (const float*)d_in[0];   // [32768, 2]
    const float* pat = (const float*)d_in[1];   // [8192, 2]
    const float* w2  = (const float*)d_in[2];   // [8192]
    float* out = (float*)d_out;                 // [32768]
    float4* c = (float4*)d_ws;                  // 8192 * 16 B = 128 KB

    prep_kernel<<<(P / 2 + 255) / 256, 256, 0, stream>>>(pat, w2, c);
    rbf_kernel<<<NBLK, THREADS, 0, stream>>>(X, c, out);
}